// Round 14
// baseline (255.991 us; speedup 1.0000x reference)
//
#include <hip/hip_runtime.h>

#define DEVFN __device__ __forceinline__

typedef __attribute__((ext_vector_type(4))) float f32x4;
typedef __attribute__((ext_vector_type(8))) short short8;
typedef __attribute__((ext_vector_type(8))) unsigned short ushort8;

constexpr int CB = 32;
constexpr int CS = 2048;
constexpr int CD = 1024;
constexpr int CU = 1024;
constexpr int CM = CB * CS;   // 65536

DEVFN unsigned f2bf_u(float f) {
    unsigned u = __float_as_uint(f);
    return (u + 0x7FFFu + ((u >> 16) & 1u)) >> 16;   // RNE f32->bf16
}
DEVFN unsigned f2bf_pack(float lo, float hi) {
    return f2bf_u(lo) | (f2bf_u(hi) << 16);
}
DEVFN uint2 cvt4(f32x4 a) {
    uint2 r;
    r.x = f2bf_pack(a[0], a[1]);
    r.y = f2bf_pack(a[2], a[3]);
    return r;
}
DEVFN float tanh_fast(float x) {
    float e = exp2f(x * 2.885390081777927f);
    return 1.0f - 2.0f * __builtin_amdgcn_rcpf(e + 1.0f);
}

// ---- bias = b1 + b2 + q@W2, two-stage split-D ----
__global__ void k_bias1(const float* __restrict__ q, const float* __restrict__ W2,
                        float* __restrict__ bpart) {
    int dc = blockIdx.x, b = blockIdx.y;   // 8 x 32
    int t = threadIdx.x;                    // 256
    __shared__ float qs[128];
    if (t < 128) qs[t] = q[b * CD + dc * 128 + t];
    __syncthreads();
    float acc0 = 0.f, acc1 = 0.f, acc2 = 0.f, acc3 = 0.f;
    const float* w2 = W2 + (size_t)(dc * 128) * CU + t;
#pragma unroll 4
    for (int d = 0; d < 128; ++d) {
        float qv = qs[d];
        const float* r = w2 + (size_t)d * CU;
        acc0 += qv * r[0];
        acc1 += qv * r[256];
        acc2 += qv * r[512];
        acc3 += qv * r[768];
    }
    float* o = bpart + (size_t)(b * 8 + dc) * CU + t;
    o[0] = acc0; o[256] = acc1; o[512] = acc2; o[768] = acc3;
}

__global__ void k_bias2(const float* __restrict__ bpart, const float* __restrict__ b1,
                        const float* __restrict__ b2, float* __restrict__ bias) {
    int idx = blockIdx.x * 256 + threadIdx.x;   // 32768
    int b = idx >> 10, u = idx & 1023;
    float s = b1[u] + b2[u];
#pragma unroll
    for (int dc = 0; dc < 8; ++dc) s += bpart[(size_t)(b * 8 + dc) * CU + u];
    bias[idx] = s;
}

// ---- pack W1[D][U] f32 -> bf16, per-64K-tile frag-linear ----
// rec = kt*128 + cb*32 + jj*2 + h  (kt 0..15, cb 0..3, jj 0..15, h 0..1)
// shorts idx = rec*512 + l*8 + e ; u = cb*256 + jj*16 + (l&15) ;
// d = kt*64 + h*32 + (l>>4)*8 + e
__global__ void k_packW1(const float* __restrict__ W1, unsigned short* __restrict__ W1p) {
    int tid = blockIdx.x * 256 + threadIdx.x;   // 131072 threads, 8 shorts each
    int o8 = tid * 8;
    int l  = tid & 63;
    int fr = tid >> 6;          // rec 0..2047
    int h  = fr & 1;
    int jj = (fr >> 1) & 15;
    int cb = (fr >> 5) & 3;
    int kt = fr >> 7;
    int u  = cb * 256 + jj * 16 + (l & 15);
    int d0 = kt * 64 + h * 32 + (l >> 4) * 8;
    ushort8 v;
#pragma unroll
    for (int e = 0; e < 8; ++e)
        v[e] = (unsigned short)f2bf_u(W1[(size_t)(d0 + e) * CU + u]);
    *(ushort8*)(W1p + o8) = v;
}

// ---- fused score GEMM v11: m201-style 8-phase (v10 + B-addressing FIX:
// read stride now matches pack layout: kt stride 65536 shorts, cb stride 32 recs).
// Block = 512 thr (8 waves, 2M x 4N), tile 256x256, BK=64 (16 K-tiles,
// 4 phases each of 16 MFMA). A: reg-staged f32->bf16, LDS dbuf 2x32KB, XOR
// slot swizzle, b64 writes. B: global->reg (h0 dbuf + in-tile h1).
__global__ __launch_bounds__(512, 2) void k_score(
    const float* __restrict__ values, const unsigned short* __restrict__ W1p,
    const float* __restrict__ bias, const float* __restrict__ V,
    float* __restrict__ score4) {
    __shared__ __align__(16) char smem[65536];   // A bufs: [0,32K) and [32K,64K)

    const int t = threadIdx.x;
    const int w = t >> 6, l = t & 63;
    const int wr = w >> 2, wc = w & 3;
    const int p = blockIdx.x;                   // 1024 blocks
    const int L = (p & 7) * 128 + (p >> 3);     // bijective XCD swizzle
    const int mt = L >> 2;                      // m-tile 0..255 (4 cb share A)
    const int cb = L & 3;
    const int ph = mt & 15;                     // K-phase rotation
    const int m0 = mt * 256;
    const int bb = m0 >> 11;                    // batch (256 divides 2048)

    // A global: round m covers row m0 + m*32 + w*4 + (l>>4), cols (l&15)*4..+4
    const float* aLdT = values + (size_t)(m0 + w * 4 + (l >> 4)) * CD + (l & 15) * 4;
    // A ds_write: frag f = m*4 + wr*2 + h; slot=(rowin|(g<<4))^(g<<1)^(h<<2)
    const int rowin = wc * 4 + (l >> 4);
    const int gW = ((l & 15) >> 1) & 3;
    const int hW = (l & 15) >> 3;
    const int aWr = (wr * 2 + hW) * 1024
                  + (((rowin | (gW << 4)) ^ (gW << 1) ^ (hW << 2)) << 4)
                  + (l & 1) * 8;               // + m*4096 per round
    // A ds_read: frag f = (wr*8+il)*2 + h ; rdslot = l ^ ((l>>4)<<1) ^ (h<<2)
    const int rs0 = (((l & 15) | ((l >> 4) << 4)) ^ ((l >> 4) << 1)) << 4;
    const int rs1 = ((((l & 15) | ((l >> 4) << 4)) ^ ((l >> 4) << 1)) ^ 4) << 4;
    const int aRd0 = wr * 16384 + rs0;          // h=0 ; + il*2048
    const int aRd1 = wr * 16384 + 1024 + rs1;   // h=1 ; + il*2048
    // B: rec = kt*128 + cb*32 + wc*8 + j*2 + h ; shorts = rec*512 + l*8
    const unsigned short* bW = W1p + (size_t)(cb * 32 + wc * 8) * 512 + l * 8;

    f32x4 acc[8][4];
#pragma unroll
    for (int i = 0; i < 8; ++i)
#pragma unroll
        for (int j = 0; j < 4; ++j) acc[i][j] = f32x4{0.f, 0.f, 0.f, 0.f};

    short8 bA[4], bB[4], bH1[4];                // h0 dbuf + shared h1
    f32x4 a0, a1, a2, a3, a4, a5, a6, a7;       // A holds (2 batches)

    // ---- prologue: A(0) full stage -> buf0 ; bA = tile ph h0 ----
    {
        const float* ap = aLdT + (size_t)ph * 64;
        a0 = *(const f32x4*)(ap);
        a1 = *(const f32x4*)(ap + 32768);
        a2 = *(const f32x4*)(ap + 65536);
        a3 = *(const f32x4*)(ap + 98304);
        a4 = *(const f32x4*)(ap + 131072);
        a5 = *(const f32x4*)(ap + 163840);
        a6 = *(const f32x4*)(ap + 196608);
        a7 = *(const f32x4*)(ap + 229376);
        *(uint2*)(smem + aWr)          = cvt4(a0);
        *(uint2*)(smem + aWr + 4096)   = cvt4(a1);
        *(uint2*)(smem + aWr + 8192)   = cvt4(a2);
        *(uint2*)(smem + aWr + 12288)  = cvt4(a3);
        *(uint2*)(smem + aWr + 16384)  = cvt4(a4);
        *(uint2*)(smem + aWr + 20480)  = cvt4(a5);
        *(uint2*)(smem + aWr + 24576)  = cvt4(a6);
        *(uint2*)(smem + aWr + 28672)  = cvt4(a7);
        const unsigned short* bs = bW + (size_t)ph * 65536;
#pragma unroll
        for (int j = 0; j < 4; ++j)
            bA[j] = *(const short8*)(bs + j * 1024);
        asm volatile("s_waitcnt lgkmcnt(0)" ::: "memory");
        asm volatile("s_barrier" ::: "memory");
    }

#define PH_SYNC()                                                                   \
    __builtin_amdgcn_sched_barrier(0);                                              \
    asm volatile("s_barrier" ::: "memory");                                         \
    asm volatile("s_waitcnt lgkmcnt(0)" ::: "memory");                              \
    __builtin_amdgcn_sched_barrier(0);

#define MFMA4(FR, II, SET)                                                          \
    _Pragma("unroll")                                                               \
    for (int j = 0; j < 4; ++j)                                                     \
        acc[II][j] = __builtin_amdgcn_mfma_f32_16x16x32_bf16(FR, SET[j], acc[II][j], 0, 0, 0);

#define TILE(TT, RB, WB, H0C, H0N, DO)                                              \
    {                                                                               \
        const int kN = ((TT) + 1 + ph) & 15;                                        \
        const int kC = ((TT) + ph) & 15;                                            \
        { /* q0: aF h0 i0-3 ; load bH1(T) ; issue A batch0 */                       \
            short8 f0 = *(const short8*)((RB) + aRd0);                              \
            short8 f1 = *(const short8*)((RB) + aRd0 + 2048);                       \
            short8 f2 = *(const short8*)((RB) + aRd0 + 4096);                       \
            short8 f3 = *(const short8*)((RB) + aRd0 + 6144);                       \
            {                                                                       \
                const unsigned short* bs = bW + (size_t)kC * 65536 + 512;           \
                _Pragma("unroll")                                                   \
                for (int j = 0; j < 4; ++j)                                         \
                    bH1[j] = *(const short8*)(bs + j * 1024);                       \
            }                                                                       \
            if (DO) {                                                               \
                const float* ap = aLdT + (size_t)kN * 64;                           \
                a0 = *(const f32x4*)(ap);                                           \
                a1 = *(const f32x4*)(ap + 32768);                                   \
                a2 = *(const f32x4*)(ap + 65536);                                   \
                a3 = *(const f32x4*)(ap + 98304);                                   \
            }                                                                       \
            PH_SYNC()                                                               \
            __builtin_amdgcn_s_setprio(1);                                          \
            MFMA4(f0, 0, H0C) MFMA4(f1, 1, H0C) MFMA4(f2, 2, H0C) MFMA4(f3, 3, H0C)\
            __builtin_amdgcn_s_setprio(0);                                          \
            __builtin_amdgcn_sched_barrier(0);                                      \
            asm volatile("s_barrier" ::: "memory");                                 \
        }                                                                           \
        { /* q1: aF h0 i4-7 ; issue A batch1 */                                     \
            short8 f4 = *(const short8*)((RB) + aRd0 + 8192);                       \
            short8 f5 = *(const short8*)((RB) + aRd0 + 10240);                      \
            short8 f6 = *(const short8*)((RB) + aRd0 + 12288);                      \
            short8 f7 = *(const short8*)((RB) + aRd0 + 14336);                      \
            if (DO) {                                                               \
                const float* ap = aLdT + (size_t)kN * 64;                           \
                a4 = *(const f32x4*)(ap + 131072);                                  \
                a5 = *(const f32x4*)(ap + 163840);                                  \
                a6 = *(const f32x4*)(ap + 196608);                                  \
                a7 = *(const f32x4*)(ap + 229376);                                  \
            }                                                                       \
            PH_SYNC()                                                               \
            __builtin_amdgcn_s_setprio(1);                                          \
            MFMA4(f4, 4, H0C) MFMA4(f5, 5, H0C) MFMA4(f6, 6, H0C) MFMA4(f7, 7, H0C)\
            __builtin_amdgcn_s_setprio(0);                                          \
            __builtin_amdgcn_sched_barrier(0);                                      \
            asm volatile("s_barrier" ::: "memory");                                 \
        }                                                                           \
        { /* q2: aF h1 i0-3 ; cvt+write batch0 -> WB */                             \
            short8 f0 = *(const short8*)((RB) + aRd1);                              \
            short8 f1 = *(const short8*)((RB) + aRd1 + 2048);                       \
            short8 f2 = *(const short8*)((RB) + aRd1 + 4096);                       \
            short8 f3 = *(const short8*)((RB) + aRd1 + 6144);                       \
            if (DO) {                                                               \
                *(uint2*)((WB) + aWr)         = cvt4(a0);                           \
                *(uint2*)((WB) + aWr + 4096)  = cvt4(a1);                           \
                *(uint2*)((WB) + aWr + 8192)  = cvt4(a2);                           \
                *(uint2*)((WB) + aWr + 12288) = cvt4(a3);                           \
            }                                                                       \
            PH_SYNC()                                                               \
            __builtin_amdgcn_s_setprio(1);                                          \
            MFMA4(f0, 0, bH1) MFMA4(f1, 1, bH1) MFMA4(f2, 2, bH1) MFMA4(f3, 3, bH1)\
            __builtin_amdgcn_s_setprio(0);                                          \
            __builtin_amdgcn_sched_barrier(0);                                      \
            asm volatile("s_barrier" ::: "memory");                                 \
        }                                                                           \
        { /* q3: aF h1 i4-7 ; cvt+write batch1 ; load bH0(T+1) */                   \
            short8 f4 = *(const short8*)((RB) + aRd1 + 8192);                       \
            short8 f5 = *(const short8*)((RB) + aRd1 + 10240);                      \
            short8 f6 = *(const short8*)((RB) + aRd1 + 12288);                      \
            short8 f7 = *(const short8*)((RB) + aRd1 + 14336);                      \
            if (DO) {                                                               \
                *(uint2*)((WB) + aWr + 16384) = cvt4(a4);                           \
                *(uint2*)((WB) + aWr + 20480) = cvt4(a5);                           \
                *(uint2*)((WB) + aWr + 24576) = cvt4(a6);                           \
                *(uint2*)((WB) + aWr + 28672) = cvt4(a7);                           \
                const unsigned short* bs = bW + (size_t)kN * 65536;                 \
                _Pragma("unroll")                                                   \
                for (int j = 0; j < 4; ++j)                                         \
                    H0N[j] = *(const short8*)(bs + j * 1024);                       \
            }                                                                       \
            PH_SYNC()                                                               \
            __builtin_amdgcn_s_setprio(1);                                          \
            MFMA4(f4, 4, bH1) MFMA4(f5, 5, bH1) MFMA4(f6, 6, bH1) MFMA4(f7, 7, bH1)\
            __builtin_amdgcn_s_setprio(0);                                          \
            __builtin_amdgcn_sched_barrier(0);                                      \
            asm volatile("s_barrier" ::: "memory");                                 \
        }                                                                           \
    }

    for (int tt = 0; tt < 14; tt += 2) {
        TILE(tt,     smem,         smem + 32768, bA, bB, 1)
        TILE(tt + 1, smem + 32768, smem,         bB, bA, 1)
    }
    TILE(14, smem,         smem + 32768, bA, bB, 1)
    TILE(15, smem + 32768, smem,         bB, bA, 0)
#undef TILE
#undef MFMA4
#undef PH_SYNC

    // ---- epilogue: score rows m0 + wr*128 + i*16 + (l>>4)*4 + rr ----
    float* red = (float*)smem;   // [8][128] f32 = 4 KB (buf0 free)
    {
#pragma unroll
        for (int i = 0; i < 8; ++i) {
            float pr[4] = {0.f, 0.f, 0.f, 0.f};
#pragma unroll
            for (int j = 0; j < 4; ++j) {
                const int col = cb * 256 + wc * 64 + j * 16 + (l & 15);
                const float vv = V[col];
                const float bz = bias[bb * CU + col];
#pragma unroll
                for (int rr = 0; rr < 4; ++rr)
                    pr[rr] += vv * tanh_fast(acc[i][j][rr] + bz);
            }
#pragma unroll
            for (int rr = 0; rr < 4; ++rr) {
                float v = pr[rr];
                v += __shfl_xor(v, 1);
                v += __shfl_xor(v, 2);
                v += __shfl_xor(v, 4);
                v += __shfl_xor(v, 8);
                if ((l & 15) == 0)
                    red[w * 128 + i * 16 + (l >> 4) * 4 + rr] = v;
            }
        }
    }
    __syncthreads();
    if (t < 256) {
        const int wrT = t >> 7, r128 = t & 127;
        float sv = red[(wrT * 4 + 0) * 128 + r128] + red[(wrT * 4 + 1) * 128 + r128]
                 + red[(wrT * 4 + 2) * 128 + r128] + red[(wrT * 4 + 3) * 128 + r128];
        score4[(size_t)cb * CM + m0 + t] = sv;
    }
}

// ---- softmax over S per batch; sums the 4 cb slices ----
__global__ void k_softmax(const float* __restrict__ score4, float* __restrict__ wts) {
    int b = blockIdx.x, t = threadIdx.x;   // 1024 threads
    int i0 = b * CS + t, i1 = i0 + 1024;
    float s0 = score4[i0] + score4[CM + i0] + score4[2 * CM + i0] + score4[3 * CM + i0];
    float s1 = score4[i1] + score4[CM + i1] + score4[2 * CM + i1] + score4[3 * CM + i1];
    __shared__ float red[16];
    int wv = t >> 6, ln = t & 63;
    float m = fmaxf(s0, s1);
#pragma unroll
    for (int o = 32; o >= 1; o >>= 1) m = fmaxf(m, __shfl_xor(m, o));
    if (ln == 0) red[wv] = m;
    __syncthreads();
    float M = red[0];
#pragma unroll
    for (int k = 1; k < 16; ++k) M = fmaxf(M, red[k]);
    float e0 = __expf(s0 - M), e1 = __expf(s1 - M);
    float sm = e0 + e1;
#pragma unroll
    for (int o = 32; o >= 1; o >>= 1) sm += __shfl_xor(sm, o);
    __syncthreads();
    if (ln == 0) red[wv] = sm;
    __syncthreads();
    float T = 0.f;
#pragma unroll
    for (int k = 0; k < 16; ++k) T += red[k];
    float inv = 1.0f / T;
    wts[i0] = e0 * inv;
    wts[i1] = e1 * inv;
}

// ---- context ----
__global__ void k_ctx_part(const float* __restrict__ values, const float* __restrict__ wts,
                           float* __restrict__ part) {
    int b = blockIdx.y, sc = blockIdx.x;   // 32 x 32
    int t = threadIdx.x;                    // 256, float4 each -> full D
    const float* vb = values + ((size_t)b * CS + sc * 64) * CD + t * 4;
    const float* wb = wts + b * CS + sc * 64;
    f32x4 a = {0.f, 0.f, 0.f, 0.f};
#pragma unroll 8
    for (int s = 0; s < 64; ++s) {
        float wgt = wb[s];
        f32x4 v = *(const f32x4*)(vb + (size_t)s * CD);
        a += v * wgt;
    }
    *(f32x4*)(part + (size_t)(b * 32 + sc) * CD + t * 4) = a;
}

__global__ void k_ctx_red(const float* __restrict__ part, float* __restrict__ ctx) {
    int idx = blockIdx.x * 256 + threadIdx.x;   // 32768
    int b = idx >> 10, d = idx & 1023;
    float s = 0.f;
#pragma unroll 8
    for (int c = 0; c < 32; ++c) s += part[(size_t)(b * 32 + c) * CD + d];
    ctx[idx] = s;
}

extern "C" void kernel_launch(void* const* d_in, const int* in_sizes, int n_in,
                              void* d_out, int out_size, void* d_ws, size_t ws_size,
                              hipStream_t stream) {
    const float* query  = (const float*)d_in[0];
    const float* values = (const float*)d_in[1];
    const float* W1     = (const float*)d_in[2];
    const float* b1     = (const float*)d_in[3];
    const float* W2     = (const float*)d_in[4];
    const float* b2     = (const float*)d_in[5];
    const float* V      = (const float*)d_in[6];
    // d_in[7] = bV: softmax shift-invariant, score not an output -> unused

    float* out = (float*)d_out;
    float* ctx = out;            // [32][1024]
    float* wts = out + 32768;    // [32][2048]

    char* ws = (char*)d_ws;
    float*          score4 = (float*)ws;                                       // 1 MB
    float*          bias   = (float*)(ws + (1 << 20));                         // 128 KB
    unsigned short* W1p    = (unsigned short*)(ws + (1 << 20) + (1 << 17));    // 2 MB
    float*          part   = (float*)(ws + (1 << 20) + (1 << 17) + (1 << 21)); // 4 MB
    float*          bpart  = part;   // 1 MB, consumed before k_ctx_part

    k_bias1<<<dim3(8, 32), 256, 0, stream>>>(query, W2, bpart);
    k_bias2<<<128, 256, 0, stream>>>(bpart, b1, b2, bias);
    k_packW1<<<512, 256, 0, stream>>>(W1, W1p);
    k_score<<<1024, 512, 0, stream>>>(values, W1p, bias, V, score4);
    k_softmax<<<32, 1024, 0, stream>>>(score4, wts);
    k_ctx_part<<<dim3(32, 32), 256, 0, stream>>>(values, wts, part);
    k_ctx_red<<<128, 256, 0, stream>>>(part, ctx);
}